// Round 4
// baseline (364.411 us; speedup 1.0000x reference)
//
#include <hip/hip_runtime.h>
#include <math.h>

#define B 2
#define S 2048
#define HID 2048
#define NH 32
#define NKV 8
#define HD 64
#define NREP 4

typedef __bf16 bf16_t;
typedef bf16_t bf16x8 __attribute__((ext_vector_type(8)));
typedef bf16_t bf16x4 __attribute__((ext_vector_type(4)));
typedef bf16_t bf16x2 __attribute__((ext_vector_type(2)));
typedef float floatx4 __attribute__((ext_vector_type(4)));

// async global->LDS, 16 B per lane. LDS dest is wave-uniform base + lane*16,
// so the LDS layout must be lane-contiguous in issue order (all uses comply).
__device__ __forceinline__ void gld_lds16(const void* g, void* l) {
    __builtin_amdgcn_global_load_lds(
        (const __attribute__((address_space(1))) void*)g,
        (__attribute__((address_space(3))) void*)l, 16, 0, 0);
}

__device__ __forceinline__ int pack2(float a, float b) {
    bf16x2 v; v[0] = (bf16_t)a; v[1] = (bf16_t)b;
    return __builtin_bit_cast(int, v);
}

__device__ __forceinline__ bf16x8 cat8(bf16x4 lo, bf16x4 hi) {
    int2 a = __builtin_bit_cast(int2, lo), b = __builtin_bit_cast(int2, hi);
    int4 w; w.x = a.x; w.y = a.y; w.z = b.x; w.w = b.y;
    return __builtin_bit_cast(bf16x8, w);
}

__device__ __forceinline__ bf16x8 cat8i(int2 lo, int2 hi) {
    int4 w; w.x = lo.x; w.y = lo.y; w.z = hi.x; w.w = hi.y;
    return __builtin_bit_cast(bf16x8, w);
}

// ---------------------------------------------------------------------------
// Fused fp32->bf16 casts: x | wq | wk | wv -> xb, wqkvb ; wo -> wob
// ---------------------------------------------------------------------------
__global__ __launch_bounds__(256) void cast_all(const float* __restrict__ x,
                                                const float* __restrict__ wq,
                                                const float* __restrict__ wk,
                                                const float* __restrict__ wv,
                                                const float* __restrict__ wo,
                                                bf16_t* __restrict__ xb,
                                                bf16_t* __restrict__ wqkvb,
                                                bf16_t* __restrict__ wob) {
    int gid = blockIdx.x * 256 + threadIdx.x;   // 2,359,296 threads total
    const float* src; bf16_t* dst; int idx;
    if (gid < 1048576)      { src = x;  dst = xb;               idx = gid; }
    else if (gid < 1572864) { src = wq; dst = wqkvb;            idx = gid - 1048576; }
    else if (gid < 1703936) { src = wk; dst = wqkvb + 4194304;  idx = gid - 1572864; }
    else if (gid < 1835008) { src = wv; dst = wqkvb + 5242880;  idx = gid - 1703936; }
    else                    { src = wo; dst = wob;              idx = gid - 1835008; }
    size_t i = (size_t)idx * 8;
    float4 f0 = *(const float4*)(src + i);
    float4 f1 = *(const float4*)(src + i + 4);
    bf16x8 v;
    v[0] = (bf16_t)f0.x; v[1] = (bf16_t)f0.y; v[2] = (bf16_t)f0.z; v[3] = (bf16_t)f0.w;
    v[4] = (bf16_t)f1.x; v[5] = (bf16_t)f1.y; v[6] = (bf16_t)f1.z; v[7] = (bf16_t)f1.w;
    *(bf16x8*)(dst + i) = v;
}

// ---------------------------------------------------------------------------
// MFMA GEMM: C[M,N] = A[M,K]*W[N,K]^T, bf16 in, fp32 acc.
// 128x128 tile, 256 thr = 4 waves (2x2 of 64x64), BK=64 as TWO m97-style
// [128][32] panels (identical bank pattern, half the barriers vs BK=32).
// MODE_QKV: N=3072 fused q|k|v projection. Wave's 64 cols = one head:
//   hh<32 : q head, RoPE + 0.125*log2(e) -> qb[b][h][s][d]  (attn uses exp2)
//   32..39: k head, RoPE                 -> kb[b][kvh][s][d]
//   40..47: v head, transposed           -> vtb[b][kvh][d][s]
// MODE_OUT: fp32 C[M][N].
// ---------------------------------------------------------------------------
#define TM 128
#define TN 128
#define BK 64

enum { MODE_QKV = 0, MODE_OUT = 2 };

template <int MODE>
__global__ __launch_bounds__(256) void gemm_mfma(const bf16_t* __restrict__ A,
                                                 const bf16_t* __restrict__ W,
                                                 void* __restrict__ outQ,
                                                 bf16_t* __restrict__ outK,
                                                 bf16_t* __restrict__ outV,
                                                 const float* __restrict__ cosp,
                                                 const float* __restrict__ sinp,
                                                 int M, int N, int K) {
    __shared__ __align__(16) bf16_t As[2 * TM * 32];   // [panel][row][32]
    __shared__ __align__(16) bf16_t Ws[2 * TN * 32];
    const int t    = threadIdx.x;
    const int wave = t >> 6, lane = t & 63;
    const int quad = lane >> 4, l16 = lane & 15;
    const int m0 = blockIdx.y * TM, n0 = blockIdx.x * TN;
    const int wm = (wave >> 1) * 64, wn = (wave & 1) * 64;

    floatx4 zero4 = {0.f, 0.f, 0.f, 0.f};
    floatx4 acc[4][4];
    #pragma unroll
    for (int i = 0; i < 4; ++i)
        #pragma unroll
        for (int j = 0; j < 4; ++j) acc[i][j] = zero4;

    // staging: thread t covers row t>>2 (+64 on 2nd issue), 16B chunk t&3
    const int r4 = t >> 2;
    const int c8 = (t & 3) * 8;
    const bf16_t* Arow = A + (size_t)(m0 + r4) * K + c8;
    const bf16_t* Wrow = W + (size_t)(n0 + r4) * K + c8;

    for (int k0 = 0; k0 < K; k0 += BK) {
        #pragma unroll
        for (int ks = 0; ks < 2; ++ks) {
            gld_lds16(Arow + k0 + ks * 32,          As + ks * 4096 + t * 8);
            gld_lds16(Arow + 64 * K + k0 + ks * 32, As + ks * 4096 + 2048 + t * 8);
            gld_lds16(Wrow + k0 + ks * 32,          Ws + ks * 4096 + t * 8);
            gld_lds16(Wrow + 64 * K + k0 + ks * 32, Ws + ks * 4096 + 2048 + t * 8);
        }
        __syncthreads();
        #pragma unroll
        for (int ks = 0; ks < 2; ++ks) {
            bf16x8 af[4], bfr[4];
            #pragma unroll
            for (int i = 0; i < 4; ++i)
                af[i] = *(bf16x8*)&As[ks * 4096 + (wm + i * 16 + l16) * 32 + quad * 8];
            #pragma unroll
            for (int j = 0; j < 4; ++j)
                bfr[j] = *(bf16x8*)&Ws[ks * 4096 + (wn + j * 16 + l16) * 32 + quad * 8];
            #pragma unroll
            for (int i = 0; i < 4; ++i)
                #pragma unroll
                for (int j = 0; j < 4; ++j)
                    acc[i][j] = __builtin_amdgcn_mfma_f32_16x16x32_bf16(af[i], bfr[j], acc[i][j], 0, 0, 0);
        }
        __syncthreads();
    }

    if constexpr (MODE == MODE_OUT) {
        float* C = (float*)outQ;
        #pragma unroll
        for (int i = 0; i < 4; ++i)
            #pragma unroll
            for (int r = 0; r < 4; ++r) {
                int row = m0 + wm + i * 16 + quad * 4 + r;
                #pragma unroll
                for (int j = 0; j < 4; ++j)
                    C[(size_t)row * N + n0 + wn + j * 16 + l16] = acc[i][j][r];
            }
    } else {
        const int hh = (n0 + wn) / 64;   // 0..47
        #pragma unroll
        for (int i = 0; i < 4; ++i)
            #pragma unroll
            for (int r = 0; r < 4; ++r) {
                int m = m0 + wm + i * 16 + quad * 4 + r;
                int b = m / S, s = m % S;
                if (hh < NH + NKV) {     // q or k head: RoPE
                    bf16_t* base;
                    float sc;
                    if (hh < NH) {
                        base = (bf16_t*)outQ + ((size_t)(b * NH + hh) * S + s) * HD;
                        sc = 0.18033688011f;   // 0.125 * log2(e): attn uses exp2
                    } else {
                        base = outK + ((size_t)(b * NKV + (hh - NH)) * S + s) * HD;
                        sc = 1.0f;
                    }
                    #pragma unroll
                    for (int j = 0; j < 2; ++j) {  // pair (d, d+32) = frags (j, j+2)
                        int d = j * 16 + l16;
                        float x1 = acc[i][j][r], x2 = acc[i][j + 2][r];
                        float c1 = cosp[s * HD + d],      s1 = sinp[s * HD + d];
                        float c2 = cosp[s * HD + d + 32], s2 = sinp[s * HD + d + 32];
                        base[d]      = (bf16_t)((x1 * c1 - x2 * s1) * sc);
                        base[d + 32] = (bf16_t)((x2 * c2 + x1 * s2) * sc);
                    }
                } else {                 // v head: write transposed [b][kvh][d][s]
                    int kvh = hh - NH - NKV;
                    bf16_t* vb = outV + ((size_t)(b * NKV + kvh) * HD) * S + s;
                    #pragma unroll
                    for (int j = 0; j < 4; ++j)
                        vb[(size_t)(j * 16 + l16) * S] = (bf16_t)acc[i][j][r];
                }
            }
    }
}

// ---------------------------------------------------------------------------
// Flash attention, bf16 MFMA, transposed formulation, no running max (scores
// |s|~5 bounded; fp32 exp2 safe; softmax shift-invariant).
// R12: REGISTER-RESIDENT P (no Pq LDS at all) + 4-wave blocks.
//   Key identity: swapped QK^T (mfma(K,Q)) puts P[q=l16][keys quad*4+r]
//   in-lane; the PV B-frag needs P[q=l16][k-slot (quad,e)]. MFMA's k-dim is
//   an arbitrary index, so apply permutation pi(quad,e) = {4quad+e (e<4),
//   16+4quad+e-4 (e>=4)} consistently to BOTH PV operands:
//     - B-frag pb[qj][ks] = concat(pk[2ks][qj], pk[2ks+1][qj]) -- exactly the
//       packed bf16 registers the QK output already sits in. Zero shuffles.
//     - A-frag va = concat of TWO ds_read_b64 from Vs at panel keys 4quad
//       and 16+4quad (Vs layout unchanged).
//   This deletes 16 ds_write_b64 + 8 ds_read_b128 per tile, their bank
//   conflicts (the bulk of 1.05e7 cycles), and 9.2 KB LDS.
//   LDS 16.4 KB -> blocks widened to 4 waves x 32 q = 128 q: same grid 1024,
//   same staging traffic, but 16 waves/CU = 4 waves/SIMD (was 2) for latency
//   hiding. __launch_bounds__(256,4) caps VGPR at 128 (est ~110).
//   Staggered staging (R11) + XCD remap (FETCH 41->12 MB verified) + setprio
//   retained.
// ---------------------------------------------------------------------------
__global__ __launch_bounds__(256, 4) void attn_mfma(const bf16_t* __restrict__ Q,
                                                    const bf16_t* __restrict__ Kb,
                                                    const bf16_t* __restrict__ Vt,
                                                    bf16_t* __restrict__ Ob) {
    __shared__ __align__(16) bf16_t Ks[2 * 64 * 32];   // [ks: d-half][key 64][d 32]
    __shared__ __align__(16) bf16_t Vs[2 * 64 * 32];   // [ks: key-half][d 64][key 32]
    const int t    = threadIdx.x;        // 0..255
    const int wave = t >> 6, lane = t & 63;
    const int quad = lane >> 4, l16 = lane & 15;

    // XCD-partitioned bijective remap (unchanged from R11): each XCD sees
    // exactly 2 (b,kvh) combos -> 1 MB K/V working set inside its 4 MB L2.
    const int flat  = blockIdx.y * 16 + blockIdx.x;   // 0..1023 dispatch slot
    const int local = flat >> 3;                      // 0..127 within XCD
    const int combo = (flat & 7) * 2 + (local >> 6);  // 0..15 = (b,kvh)
    const int b = combo >> 3, kvh = combo & 7;
    const int h  = kvh * NREP + ((local >> 4) & 3);
    const int q0 = (local & 15) * 128;                // block owns 128 q
    const int bh = b * NH + h;

    const bf16_t* qbase = Q + ((size_t)bh * S + q0 + wave * 32) * HD;
    const bf16_t* kbase = Kb + ((size_t)(b * NKV + kvh) * S) * HD;
    const bf16_t* vbase = Vt + (size_t)(b * NKV + kvh) * HD * S;

    // Q B-frags in registers: qf[qj][ks] = Q[q=qj*16+l16][d=ks*32+quad*8..+7]
    bf16x8 qf[2][2];
    #pragma unroll
    for (int qj = 0; qj < 2; ++qj)
        #pragma unroll
        for (int ks = 0; ks < 2; ++ks)
            qf[qj][ks] = *(const bf16x8*)(qbase + (size_t)(qj * 16 + l16) * HD + ks * 32 + quad * 8);

    floatx4 zero4 = {0.f, 0.f, 0.f, 0.f};
    floatx4 of[4][2];                    // of[di][qj]: O^T accum
    #pragma unroll
    for (int di = 0; di < 4; ++di)
        #pragma unroll
        for (int qj = 0; qj < 2; ++qj) of[di][qj] = zero4;
    float lsum[2] = {0.f, 0.f};

    // staging: 256 threads cover a full [64][32] panel per issue
    const int r4 = t >> 2;          // staging row 0..63
    const int c8 = (t & 3) * 8;     // 16B chunk within 32-wide panel

    // prologue: stage K(0); barrier drains it
    #pragma unroll
    for (int ks = 0; ks < 2; ++ks)
        gld_lds16(kbase + (size_t)r4 * HD + ks * 32 + c8, Ks + ks * 2048 + t * 8);
    __syncthreads();

    for (int kt = 0; kt < S; kt += 64) {
        // ---- phase A(t): issue Vstage(t) (Vs free: B(t-1) readers done at
        // prior barrier), then QK^T on Ks=K[t] -> exp2 -> packed P in regs.
        #pragma unroll
        for (int ks = 0; ks < 2; ++ks)
            gld_lds16(vbase + (size_t)r4 * S + kt + ks * 32 + c8, Vs + ks * 2048 + t * 8);

        int2 pk[4][2];   // pk[ki][qj]: P[q=qj*16+l16][keys 16ki+4quad+{0..3}] bf16-packed
        #pragma unroll
        for (int ki = 0; ki < 4; ++ki) {
            bf16x8 ka0 = *(bf16x8*)&Ks[0 * 2048 + (ki * 16 + l16) * 32 + quad * 8];
            bf16x8 ka1 = *(bf16x8*)&Ks[1 * 2048 + (ki * 16 + l16) * 32 + quad * 8];
            floatx4 sf[2];
            #pragma unroll
            for (int qj = 0; qj < 2; ++qj) sf[qj] = zero4;
            __builtin_amdgcn_s_setprio(1);
            #pragma unroll
            for (int qj = 0; qj < 2; ++qj)
                sf[qj] = __builtin_amdgcn_mfma_f32_16x16x32_bf16(ka0, qf[qj][0], sf[qj], 0, 0, 0);
            #pragma unroll
            for (int qj = 0; qj < 2; ++qj)
                sf[qj] = __builtin_amdgcn_mfma_f32_16x16x32_bf16(ka1, qf[qj][1], sf[qj], 0, 0, 0);
            __builtin_amdgcn_s_setprio(0);
            #pragma unroll
            for (int qj = 0; qj < 2; ++qj) {
                float p0 = __builtin_amdgcn_exp2f(sf[qj][0]);
                float p1 = __builtin_amdgcn_exp2f(sf[qj][1]);
                float p2 = __builtin_amdgcn_exp2f(sf[qj][2]);
                float p3 = __builtin_amdgcn_exp2f(sf[qj][3]);
                lsum[qj] += (p0 + p1) + (p2 + p3);
                pk[ki][qj].x = pack2(p0, p1);
                pk[ki][qj].y = pack2(p2, p3);
            }
        }
        __syncthreads();   // drains Vstage(t) -> Vs valid; all Ks reads done

        // ---- phase B(t): issue Kstage(t+1) (Ks free: A(t) readers done),
        // then O^T += V^T P^T entirely from registers + Vs b64 reads.
        if (kt + 64 < S) {
            #pragma unroll
            for (int ks = 0; ks < 2; ++ks)
                gld_lds16(kbase + (size_t)(kt + 64 + r4) * HD + ks * 32 + c8, Ks + ks * 2048 + t * 8);
        }
        #pragma unroll
        for (int ks = 0; ks < 2; ++ks) {
            __builtin_amdgcn_s_setprio(1);
            #pragma unroll
            for (int di = 0; di < 4; ++di) {
                // pi(quad,e): A-side keys {4quad..+3} U {16+4quad..+3} of panel ks
                bf16x4 vlo = *(bf16x4*)&Vs[ks * 2048 + (di * 16 + l16) * 32 + quad * 4];
                bf16x4 vhi = *(bf16x4*)&Vs[ks * 2048 + (di * 16 + l16) * 32 + 16 + quad * 4];
                bf16x8 va = cat8(vlo, vhi);
                #pragma unroll
                for (int qj = 0; qj < 2; ++qj) {
                    bf16x8 pb = cat8i(pk[2 * ks][qj], pk[2 * ks + 1][qj]);
                    of[di][qj] = __builtin_amdgcn_mfma_f32_16x16x32_bf16(va, pb, of[di][qj], 0, 0, 0);
                }
            }
            __builtin_amdgcn_s_setprio(0);
        }
        __syncthreads();   // drains Kstage(t+1) -> Ks valid; all Vs reads done
    }

    // normalize + write O^T: lane holds d = di*16+quad*4..+3 (contiguous), q fixed
    #pragma unroll
    for (int qj = 0; qj < 2; ++qj) {
        float ls = lsum[qj];
        ls += __shfl_xor(ls, 16);
        ls += __shfl_xor(ls, 32);
        float inv = 1.f / ls;
        int q = q0 + wave * 32 + qj * 16 + l16;
        bf16_t* ob = Ob + ((size_t)(b * S + q)) * HID + h * HD;
        #pragma unroll
        for (int di = 0; di < 4; ++di) {
            int2 pkv;
            pkv.x = pack2(of[di][qj][0] * inv, of[di][qj][1] * inv);
            pkv.y = pack2(of[di][qj][2] * inv, of[di][qj][3] * inv);
            *(int2*)(ob + di * 16 + quad * 4) = pkv;
        }
    }
}

// ---------------------------------------------------------------------------
extern "C" void kernel_launch(void* const* d_in, const int* in_sizes, int n_in,
                              void* d_out, int out_size, void* d_ws, size_t ws_size,
                              hipStream_t stream) {
    const float* x    = (const float*)d_in[0];
    const float* cosp = (const float*)d_in[1];
    const float* sinp = (const float*)d_in[2];
    const float* wq   = (const float*)d_in[3];
    const float* wk   = (const float*)d_in[4];
    const float* wv   = (const float*)d_in[5];
    const float* wo   = (const float*)d_in[6];
    float* out = (float*)d_out;

    char* ws = (char*)d_ws;
    // ws overlay plan (peak 46.1 MB):
    //   xb    [0,      16.8M)  -> attb overlays after qkvproj
    //   kb    [16.8M,  21.0M)
    //   vtb   [21.0M,  25.2M)
    //   wqkvb [25.2M,  37.7M)
    //   wob   [37.7M,  46.1M)
    // qb lives in d_out[0,16.8M) (dead once outproj writes fp32 there).
    bf16_t* xb    = (bf16_t*)(ws);
    bf16_t* kb    = (bf16_t*)(ws + 16777216);
    bf16_t* vtb   = (bf16_t*)(ws + 20971520);
    bf16_t* wqkvb = (bf16_t*)(ws + 25165824);
    bf16_t* wob   = (bf16_t*)(ws + 37748736);
    bf16_t* attb  = (bf16_t*)(ws);
    bf16_t* qb    = (bf16_t*)d_out;

    const int M = B * S;   // 4096

    // all casts in one launch
    cast_all<<<9216, 256, 0, stream>>>(x, wq, wk, wv, wo, xb, wqkvb, wob);

    // fused q|k|v projection, N = 3072
    gemm_mfma<MODE_QKV><<<dim3(3072 / TN, M / TM), 256, 0, stream>>>(
        xb, wqkvb, (void*)qb, kb, vtb, cosp, sinp, M, 3072, HID);

    // attention: 1024 blocks of 128 q / 4 waves; 16.4 KB LDS, reg-resident P
    attn_mfma<<<dim3(S / 128, B * NH), 256, 0, stream>>>(qb, kb, vtb, attb);

    // output projection -> d_out (fp32)
    gemm_mfma<MODE_OUT><<<dim3(2048 / TN, M / TM), 256, 0, stream>>>(
        attb, wob, (void*)out, nullptr, nullptr, nullptr, nullptr, M, 2048, HID);
}

// Round 5
// 305.797 us; speedup vs baseline: 1.1917x; 1.1917x over previous
//
#include <hip/hip_runtime.h>
#include <math.h>

#define B 2
#define S 2048
#define HID 2048
#define NH 32
#define NKV 8
#define HD 64
#define NREP 4

typedef __bf16 bf16_t;
typedef bf16_t bf16x8 __attribute__((ext_vector_type(8)));
typedef bf16_t bf16x4 __attribute__((ext_vector_type(4)));
typedef bf16_t bf16x2 __attribute__((ext_vector_type(2)));
typedef float floatx4 __attribute__((ext_vector_type(4)));

// async global->LDS, 16 B per lane. LDS dest is wave-uniform base + lane*16,
// so the LDS layout must be lane-contiguous in issue order (all uses comply).
__device__ __forceinline__ void gld_lds16(const void* g, void* l) {
    __builtin_amdgcn_global_load_lds(
        (const __attribute__((address_space(1))) void*)g,
        (__attribute__((address_space(3))) void*)l, 16, 0, 0);
}

__device__ __forceinline__ int pack2(float a, float b) {
    bf16x2 v; v[0] = (bf16_t)a; v[1] = (bf16_t)b;
    return __builtin_bit_cast(int, v);
}

__device__ __forceinline__ bf16x8 cat8i(int2 lo, int2 hi) {
    int4 w; w.x = lo.x; w.y = lo.y; w.z = hi.x; w.w = hi.y;
    return __builtin_bit_cast(bf16x8, w);
}

// ---------------------------------------------------------------------------
// Fused fp32->bf16 casts: x | wq | wk | wv -> xb, wqkvb ; wo -> wob
// ---------------------------------------------------------------------------
__global__ __launch_bounds__(256) void cast_all(const float* __restrict__ x,
                                                const float* __restrict__ wq,
                                                const float* __restrict__ wk,
                                                const float* __restrict__ wv,
                                                const float* __restrict__ wo,
                                                bf16_t* __restrict__ xb,
                                                bf16_t* __restrict__ wqkvb,
                                                bf16_t* __restrict__ wob) {
    int gid = blockIdx.x * 256 + threadIdx.x;   // 2,359,296 threads total
    const float* src; bf16_t* dst; int idx;
    if (gid < 1048576)      { src = x;  dst = xb;               idx = gid; }
    else if (gid < 1572864) { src = wq; dst = wqkvb;            idx = gid - 1048576; }
    else if (gid < 1703936) { src = wk; dst = wqkvb + 4194304;  idx = gid - 1572864; }
    else if (gid < 1835008) { src = wv; dst = wqkvb + 5242880;  idx = gid - 1703936; }
    else                    { src = wo; dst = wob;              idx = gid - 1835008; }
    size_t i = (size_t)idx * 8;
    float4 f0 = *(const float4*)(src + i);
    float4 f1 = *(const float4*)(src + i + 4);
    bf16x8 v;
    v[0] = (bf16_t)f0.x; v[1] = (bf16_t)f0.y; v[2] = (bf16_t)f0.z; v[3] = (bf16_t)f0.w;
    v[4] = (bf16_t)f1.x; v[5] = (bf16_t)f1.y; v[6] = (bf16_t)f1.z; v[7] = (bf16_t)f1.w;
    *(bf16x8*)(dst + i) = v;
}

// ---------------------------------------------------------------------------
// MFMA GEMM: C[M,N] = A[M,K]*W[N,K]^T, bf16 in, fp32 acc.
// 128x128 tile, 256 thr = 4 waves (2x2 of 64x64), BK=64 as TWO m97-style
// [128][32] panels (identical bank pattern, half the barriers vs BK=32).
// MODE_QKV: N=3072 fused q|k|v projection. Wave's 64 cols = one head:
//   hh<32 : q head, RoPE + 0.125*log2(e) -> qb[b][h][s][d]  (attn uses exp2)
//   32..39: k head, RoPE                 -> kb[b][kvh][s][d]
//   40..47: v head, transposed + sigma-PERMUTED keys -> vtb[b][kvh][d][ps]
//     (within each 64-key tile, each 32-key panel stored in sigma order:
//      sigma(8q+e) = 4q+e (e<4) | 16+4q+e-4 (e>=4), so attn's linear
//      gld_lds staging yields panels whose b128 read at quad*16B supplies
//      exactly the keys the register-resident P fragments hold. This keeps
//      PV's V read a single conflict-benign b128 -- R12's two b64 reads
//      were an 8-way bank conflict, 6.3e7 cycles.)
// MODE_OUT: fp32 C[M][N].
// ---------------------------------------------------------------------------
#define TM 128
#define TN 128
#define BK 64

enum { MODE_QKV = 0, MODE_OUT = 2 };

template <int MODE>
__global__ __launch_bounds__(256) void gemm_mfma(const bf16_t* __restrict__ A,
                                                 const bf16_t* __restrict__ W,
                                                 void* __restrict__ outQ,
                                                 bf16_t* __restrict__ outK,
                                                 bf16_t* __restrict__ outV,
                                                 const float* __restrict__ cosp,
                                                 const float* __restrict__ sinp,
                                                 int M, int N, int K) {
    __shared__ __align__(16) bf16_t As[2 * TM * 32];   // [panel][row][32]
    __shared__ __align__(16) bf16_t Ws[2 * TN * 32];
    const int t    = threadIdx.x;
    const int wave = t >> 6, lane = t & 63;
    const int quad = lane >> 4, l16 = lane & 15;
    const int m0 = blockIdx.y * TM, n0 = blockIdx.x * TN;
    const int wm = (wave >> 1) * 64, wn = (wave & 1) * 64;

    floatx4 zero4 = {0.f, 0.f, 0.f, 0.f};
    floatx4 acc[4][4];
    #pragma unroll
    for (int i = 0; i < 4; ++i)
        #pragma unroll
        for (int j = 0; j < 4; ++j) acc[i][j] = zero4;

    // staging: thread t covers row t>>2 (+64 on 2nd issue), 16B chunk t&3
    const int r4 = t >> 2;
    const int c8 = (t & 3) * 8;
    const bf16_t* Arow = A + (size_t)(m0 + r4) * K + c8;
    const bf16_t* Wrow = W + (size_t)(n0 + r4) * K + c8;

    for (int k0 = 0; k0 < K; k0 += BK) {
        #pragma unroll
        for (int ks = 0; ks < 2; ++ks) {
            gld_lds16(Arow + k0 + ks * 32,          As + ks * 4096 + t * 8);
            gld_lds16(Arow + 64 * K + k0 + ks * 32, As + ks * 4096 + 2048 + t * 8);
            gld_lds16(Wrow + k0 + ks * 32,          Ws + ks * 4096 + t * 8);
            gld_lds16(Wrow + 64 * K + k0 + ks * 32, Ws + ks * 4096 + 2048 + t * 8);
        }
        __syncthreads();
        #pragma unroll
        for (int ks = 0; ks < 2; ++ks) {
            bf16x8 af[4], bfr[4];
            #pragma unroll
            for (int i = 0; i < 4; ++i)
                af[i] = *(bf16x8*)&As[ks * 4096 + (wm + i * 16 + l16) * 32 + quad * 8];
            #pragma unroll
            for (int j = 0; j < 4; ++j)
                bfr[j] = *(bf16x8*)&Ws[ks * 4096 + (wn + j * 16 + l16) * 32 + quad * 8];
            #pragma unroll
            for (int i = 0; i < 4; ++i)
                #pragma unroll
                for (int j = 0; j < 4; ++j)
                    acc[i][j] = __builtin_amdgcn_mfma_f32_16x16x32_bf16(af[i], bfr[j], acc[i][j], 0, 0, 0);
        }
        __syncthreads();
    }

    if constexpr (MODE == MODE_OUT) {
        float* C = (float*)outQ;
        #pragma unroll
        for (int i = 0; i < 4; ++i)
            #pragma unroll
            for (int r = 0; r < 4; ++r) {
                int row = m0 + wm + i * 16 + quad * 4 + r;
                #pragma unroll
                for (int j = 0; j < 4; ++j)
                    C[(size_t)row * N + n0 + wn + j * 16 + l16] = acc[i][j][r];
            }
    } else {
        const int hh = (n0 + wn) / 64;   // 0..47
        #pragma unroll
        for (int i = 0; i < 4; ++i)
            #pragma unroll
            for (int r = 0; r < 4; ++r) {
                int m = m0 + wm + i * 16 + quad * 4 + r;
                int b = m / S, s = m % S;
                if (hh < NH + NKV) {     // q or k head: RoPE
                    bf16_t* base;
                    float sc;
                    if (hh < NH) {
                        base = (bf16_t*)outQ + ((size_t)(b * NH + hh) * S + s) * HD;
                        sc = 0.18033688011f;   // 0.125 * log2(e): attn uses exp2
                    } else {
                        base = outK + ((size_t)(b * NKV + (hh - NH)) * S + s) * HD;
                        sc = 1.0f;
                    }
                    #pragma unroll
                    for (int j = 0; j < 2; ++j) {  // pair (d, d+32) = frags (j, j+2)
                        int d = j * 16 + l16;
                        float x1 = acc[i][j][r], x2 = acc[i][j + 2][r];
                        float c1 = cosp[s * HD + d],      s1 = sinp[s * HD + d];
                        float c2 = cosp[s * HD + d + 32], s2 = sinp[s * HD + d + 32];
                        base[d]      = (bf16_t)((x1 * c1 - x2 * s1) * sc);
                        base[d + 32] = (bf16_t)((x2 * c2 + x1 * s2) * sc);
                    }
                } else {                 // v head: sigma-permuted transposed write
                    int kvh = hh - NH - NKV;
                    // ps = key s with its 32-key panel position sigma^-1-mapped
                    int w  = s & 63, lo = w & 31;
                    int pos = (lo < 16) ? (((lo >> 2) << 3) | (lo & 3))
                                        : ((((lo - 16) >> 2) << 3) | 4 | (lo & 3));
                    int ps = (s & ~63) | ((w & 32) + pos);
                    bf16_t* vb = outV + ((size_t)(b * NKV + kvh) * HD) * S + ps;
                    #pragma unroll
                    for (int j = 0; j < 4; ++j)
                        vb[(size_t)(j * 16 + l16) * S] = (bf16_t)acc[i][j][r];
                }
            }
    }
}

// ---------------------------------------------------------------------------
// Flash attention, bf16 MFMA, transposed formulation, no running max (scores
// |s|~5 bounded; fp32 exp2 safe; softmax shift-invariant).
// R13 = R12 (register-resident P, no Pq LDS, 4-wave blocks) with the V-read
// bank conflict fixed at the source:
//   R12's pi-permutation needed V keys {4q..+3, 16+4q..+3} per lane -> two
//   ds_read_b64 at row*64B + quad*8B = 8-way bank conflict (6.3e7 cycles,
//   66% of runtime). Fix: vtb's GLOBAL layout now stores each 32-key panel
//   in sigma order (sigma(8q+e) = 4q+e | 16+4q+e-4), so after linear
//   gld_lds staging the PV A-frag is ONE b128 at row*64B + quad*16B --
//   identical bank class to the Ks reads (benign in R5). B-frag remains the
//   packed QK output registers, zero shuffles (operand pairing unchanged
//   from R12, verified: va[e] and pb[e] both carry key 32ks+sigma(8q+e)).
//   Retained: staggered staging (V during QK, K(t+1) during PV), XCD remap
//   (FETCH 41->12 MB verified), setprio, 16.4 KB LDS, 256 thr / 128 q.
// ---------------------------------------------------------------------------
__global__ __launch_bounds__(256, 4) void attn_mfma(const bf16_t* __restrict__ Q,
                                                    const bf16_t* __restrict__ Kb,
                                                    const bf16_t* __restrict__ Vt,
                                                    bf16_t* __restrict__ Ob) {
    __shared__ __align__(16) bf16_t Ks[2 * 64 * 32];   // [ks: d-half][key 64][d 32]
    __shared__ __align__(16) bf16_t Vs[2 * 64 * 32];   // [ks: key-half][d 64][sigma-key 32]
    const int t    = threadIdx.x;        // 0..255
    const int wave = t >> 6, lane = t & 63;
    const int quad = lane >> 4, l16 = lane & 15;

    // XCD-partitioned bijective remap: each XCD sees exactly 2 (b,kvh)
    // combos -> 1 MB K/V working set inside its 4 MB L2.
    const int flat  = blockIdx.y * 16 + blockIdx.x;   // 0..1023 dispatch slot
    const int local = flat >> 3;                      // 0..127 within XCD
    const int combo = (flat & 7) * 2 + (local >> 6);  // 0..15 = (b,kvh)
    const int b = combo >> 3, kvh = combo & 7;
    const int h  = kvh * NREP + ((local >> 4) & 3);
    const int q0 = (local & 15) * 128;                // block owns 128 q
    const int bh = b * NH + h;

    const bf16_t* qbase = Q + ((size_t)bh * S + q0 + wave * 32) * HD;
    const bf16_t* kbase = Kb + ((size_t)(b * NKV + kvh) * S) * HD;
    const bf16_t* vbase = Vt + (size_t)(b * NKV + kvh) * HD * S;

    // Q B-frags in registers: qf[qj][ks] = Q[q=qj*16+l16][d=ks*32+quad*8..+7]
    bf16x8 qf[2][2];
    #pragma unroll
    for (int qj = 0; qj < 2; ++qj)
        #pragma unroll
        for (int ks = 0; ks < 2; ++ks)
            qf[qj][ks] = *(const bf16x8*)(qbase + (size_t)(qj * 16 + l16) * HD + ks * 32 + quad * 8);

    floatx4 zero4 = {0.f, 0.f, 0.f, 0.f};
    floatx4 of[4][2];                    // of[di][qj]: O^T accum
    #pragma unroll
    for (int di = 0; di < 4; ++di)
        #pragma unroll
        for (int qj = 0; qj < 2; ++qj) of[di][qj] = zero4;
    float lsum[2] = {0.f, 0.f};

    // staging: 256 threads cover a full [64][32] panel per issue
    const int r4 = t >> 2;          // staging row 0..63
    const int c8 = (t & 3) * 8;     // 16B chunk within 32-wide panel

    // prologue: stage K(0); barrier drains it
    #pragma unroll
    for (int ks = 0; ks < 2; ++ks)
        gld_lds16(kbase + (size_t)r4 * HD + ks * 32 + c8, Ks + ks * 2048 + t * 8);
    __syncthreads();

    for (int kt = 0; kt < S; kt += 64) {
        // ---- phase A(t): issue Vstage(t) (Vs free: B(t-1) readers done at
        // prior barrier), then QK^T on Ks=K[t] -> exp2 -> packed P in regs.
        #pragma unroll
        for (int ks = 0; ks < 2; ++ks)
            gld_lds16(vbase + (size_t)r4 * S + kt + ks * 32 + c8, Vs + ks * 2048 + t * 8);

        int2 pk[4][2];   // pk[ki][qj]: P[q=qj*16+l16][keys 16ki+4quad+{0..3}] bf16-packed
        #pragma unroll
        for (int ki = 0; ki < 4; ++ki) {
            bf16x8 ka0 = *(bf16x8*)&Ks[0 * 2048 + (ki * 16 + l16) * 32 + quad * 8];
            bf16x8 ka1 = *(bf16x8*)&Ks[1 * 2048 + (ki * 16 + l16) * 32 + quad * 8];
            floatx4 sf[2];
            #pragma unroll
            for (int qj = 0; qj < 2; ++qj) sf[qj] = zero4;
            __builtin_amdgcn_s_setprio(1);
            #pragma unroll
            for (int qj = 0; qj < 2; ++qj)
                sf[qj] = __builtin_amdgcn_mfma_f32_16x16x32_bf16(ka0, qf[qj][0], sf[qj], 0, 0, 0);
            #pragma unroll
            for (int qj = 0; qj < 2; ++qj)
                sf[qj] = __builtin_amdgcn_mfma_f32_16x16x32_bf16(ka1, qf[qj][1], sf[qj], 0, 0, 0);
            __builtin_amdgcn_s_setprio(0);
            #pragma unroll
            for (int qj = 0; qj < 2; ++qj) {
                float p0 = __builtin_amdgcn_exp2f(sf[qj][0]);
                float p1 = __builtin_amdgcn_exp2f(sf[qj][1]);
                float p2 = __builtin_amdgcn_exp2f(sf[qj][2]);
                float p3 = __builtin_amdgcn_exp2f(sf[qj][3]);
                lsum[qj] += (p0 + p1) + (p2 + p3);
                pk[ki][qj].x = pack2(p0, p1);
                pk[ki][qj].y = pack2(p2, p3);
            }
        }
        __syncthreads();   // drains Vstage(t) -> Vs valid; all Ks reads done

        // ---- phase B(t): issue Kstage(t+1) (Ks free: A(t) readers done),
        // then O^T += V^T P^T from registers + ONE b128 Vs read per frag.
        if (kt + 64 < S) {
            #pragma unroll
            for (int ks = 0; ks < 2; ++ks)
                gld_lds16(kbase + (size_t)(kt + 64 + r4) * HD + ks * 32 + c8, Ks + ks * 2048 + t * 8);
        }
        #pragma unroll
        for (int ks = 0; ks < 2; ++ks) {
            __builtin_amdgcn_s_setprio(1);
            #pragma unroll
            for (int di = 0; di < 4; ++di) {
                // sigma-ordered panel: positions 8quad..+7 = keys {4quad..+3, 16+4quad..+3}
                bf16x8 va = *(bf16x8*)&Vs[ks * 2048 + (di * 16 + l16) * 32 + quad * 8];
                #pragma unroll
                for (int qj = 0; qj < 2; ++qj) {
                    bf16x8 pb = cat8i(pk[2 * ks][qj], pk[2 * ks + 1][qj]);
                    of[di][qj] = __builtin_amdgcn_mfma_f32_16x16x32_bf16(va, pb, of[di][qj], 0, 0, 0);
                }
            }
            __builtin_amdgcn_s_setprio(0);
        }
        __syncthreads();   // drains Kstage(t+1) -> Ks valid; all Vs reads done
    }

    // normalize + write O^T: lane holds d = di*16+quad*4..+3 (contiguous), q fixed
    #pragma unroll
    for (int qj = 0; qj < 2; ++qj) {
        float ls = lsum[qj];
        ls += __shfl_xor(ls, 16);
        ls += __shfl_xor(ls, 32);
        float inv = 1.f / ls;
        int q = q0 + wave * 32 + qj * 16 + l16;
        bf16_t* ob = Ob + ((size_t)(b * S + q)) * HID + h * HD;
        #pragma unroll
        for (int di = 0; di < 4; ++di) {
            int2 pkv;
            pkv.x = pack2(of[di][qj][0] * inv, of[di][qj][1] * inv);
            pkv.y = pack2(of[di][qj][2] * inv, of[di][qj][3] * inv);
            *(int2*)(ob + di * 16 + quad * 4) = pkv;
        }
    }
}

// ---------------------------------------------------------------------------
extern "C" void kernel_launch(void* const* d_in, const int* in_sizes, int n_in,
                              void* d_out, int out_size, void* d_ws, size_t ws_size,
                              hipStream_t stream) {
    const float* x    = (const float*)d_in[0];
    const float* cosp = (const float*)d_in[1];
    const float* sinp = (const float*)d_in[2];
    const float* wq   = (const float*)d_in[3];
    const float* wk   = (const float*)d_in[4];
    const float* wv   = (const float*)d_in[5];
    const float* wo   = (const float*)d_in[6];
    float* out = (float*)d_out;

    char* ws = (char*)d_ws;
    // ws overlay plan (peak 46.1 MB):
    //   xb    [0,      16.8M)  -> attb overlays after qkvproj
    //   kb    [16.8M,  21.0M)
    //   vtb   [21.0M,  25.2M)
    //   wqkvb [25.2M,  37.7M)
    //   wob   [37.7M,  46.1M)
    // qb lives in d_out[0,16.8M) (dead once outproj writes fp32 there).
    bf16_t* xb    = (bf16_t*)(ws);
    bf16_t* kb    = (bf16_t*)(ws + 16777216);
    bf16_t* vtb   = (bf16_t*)(ws + 20971520);
    bf16_t* wqkvb = (bf16_t*)(ws + 25165824);
    bf16_t* wob   = (bf16_t*)(ws + 37748736);
    bf16_t* attb  = (bf16_t*)(ws);
    bf16_t* qb    = (bf16_t*)d_out;

    const int M = B * S;   // 4096

    // all casts in one launch
    cast_all<<<9216, 256, 0, stream>>>(x, wq, wk, wv, wo, xb, wqkvb, wob);

    // fused q|k|v projection, N = 3072
    gemm_mfma<MODE_QKV><<<dim3(3072 / TN, M / TM), 256, 0, stream>>>(
        xb, wqkvb, (void*)qb, kb, vtb, cosp, sinp, M, 3072, HID);

    // attention: 1024 blocks of 128 q / 4 waves; 16.4 KB LDS, reg-resident P
    attn_mfma<<<dim3(S / 128, B * NH), 256, 0, stream>>>(qb, kb, vtb, attb);

    // output projection -> d_out (fp32)
    gemm_mfma<MODE_OUT><<<dim3(2048 / TN, M / TM), 256, 0, stream>>>(
        attb, wob, (void*)out, nullptr, nullptr, nullptr, nullptr, M, 2048, HID);
}